// Round 1
// baseline (369.845 us; speedup 1.0000x reference)
//
#include <hip/hip_runtime.h>

typedef short bf16x8 __attribute__((ext_vector_type(8)));
typedef float f32x4 __attribute__((ext_vector_type(4)));

#define K_CLUSTERS 512
#define DIM 64
#define ROWS_PER_BLOCK 64   // 4 subtiles of 16 rows

__device__ __forceinline__ unsigned short f32_to_bf16_rne(float f) {
    unsigned int u = __float_as_uint(f);
    u += 0x7fffu + ((u >> 16) & 1u);
    return (unsigned short)(u >> 16);
}
__device__ __forceinline__ float bf16_bits_to_f32(unsigned short h) {
    return __uint_as_float(((unsigned int)h) << 16);
}

// Centers -> bf16 hi/lo split + ||c||^2. Also zero-inits the loss accumulator.
__global__ void prep_centers(const float* __restrict__ c,
                             short* __restrict__ c_hi, short* __restrict__ c_lo,
                             float* __restrict__ c_sq, float* __restrict__ loss_out) {
    if (blockIdx.x == 0 && threadIdx.x == 0) loss_out[0] = 0.0f;
    int idx = blockIdx.x * 256 + threadIdx.x;   // covers 512*64
    float v = c[idx];
    unsigned short h = f32_to_bf16_rne(v);
    float hf = bf16_bits_to_f32(h);
    unsigned short l = f32_to_bf16_rne(v - hf);
    c_hi[idx] = (short)h;
    c_lo[idx] = (short)l;
    float s = v * v;
    #pragma unroll
    for (int off = 1; off < 64; off <<= 1) s += __shfl_xor(s, off, 64);
    if ((threadIdx.x & 63) == 0) c_sq[idx >> 6] = s;
}

// Raw barrier: LDS-only wait (lgkmcnt), NO vmcnt drain -> global q-stores keep
// draining across the barrier, overlapping the next subtile's MFMA phase.
// (__syncthreads() would emit s_waitcnt vmcnt(0) and serialize store drain.)
#define BARRIER() do {                                      \
    asm volatile("s_waitcnt lgkmcnt(0)" ::: "memory");      \
    __builtin_amdgcn_s_barrier();                           \
} while (0)

// 64 rows/block in 4 subtiles of 16; 8 waves x 64 clusters each.
// Softmax is fully in-register: per-wave (min, sum-exp) partials exchanged via
// a 1KB LDS table + rescale (replaces the 64KB/subtile dist_s round-trip).
// zsq cancels inside softmax: softmax(-(zsq+csq-2zc)) == softmax(2zc-csq);
// loss = mean(zsq) + mean(sum_j q_j*(csq_j-2cross_j)) -> zsq folded in at the end.
__global__ __launch_bounds__(512, 4)
void cluster_kernel(const float* __restrict__ z,
                    const short* __restrict__ c_hi,
                    const short* __restrict__ c_lo,
                    const float* __restrict__ c_sq,
                    float* __restrict__ q_out,
                    float* __restrict__ loss_out,
                    float inv_b) {
    __shared__ __align__(16) short a_hi_s[16][72];   // 144B rows: 16B-aligned
    __shared__ __align__(16) short a_lo_s[16][72];
    __shared__ __align__(16) float2 red_s[8][16];    // (mn_w, sum_w) per wave x row
    __shared__ float wloss_s[8];

    const int tid  = threadIdx.x;
    const int lane = tid & 63;
    const int wave = tid >> 6;
    const int m    = lane & 15;   // A row / B,C col within tile
    const int qd   = lane >> 4;   // quad
    const long rb  = (long)blockIdx.x * ROWS_PER_BLOCK;

    // ---- B fragments (64 cols/wave = 4 tiles): 64 VGPRs total hi+lo. ----
    bf16x8 bh[4][2], bl[4][2];
    float csq[4];
    #pragma unroll
    for (int t = 0; t < 4; ++t) {
        const int col = wave * 64 + t * 16 + m;
        const long boff = (long)col * DIM + qd * 8;
        #pragma unroll
        for (int kg = 0; kg < 2; ++kg) {
            bh[t][kg] = *(const bf16x8*)(c_hi + boff + kg * 32);
            bl[t][kg] = *(const bf16x8*)(c_lo + boff + kg * 32);
        }
        csq[t] = c_sq[col];
    }

    const float2* zin = (const float2*)(z + rb * DIM);   // 512 float2 / subtile
    const int srow = tid >> 5;
    const int scol = (tid & 31) * 2;

    float lsum = 0.0f;           // per-lane sum of q*(csq-2cross)
    float zpart;                 // per-thread sum of z^2 (loss separable term)

    // ---- prologue: load + stage subtile 0 ----
    float2 v = zin[tid];
    zpart = v.x * v.x + v.y * v.y;
    {
        unsigned short hx = f32_to_bf16_rne(v.x);
        unsigned short lx = f32_to_bf16_rne(v.x - bf16_bits_to_f32(hx));
        unsigned short hy = f32_to_bf16_rne(v.y);
        unsigned short ly = f32_to_bf16_rne(v.y - bf16_bits_to_f32(hy));
        *(unsigned int*)&a_hi_s[srow][scol] = (unsigned int)hx | ((unsigned int)hy << 16);
        *(unsigned int*)&a_lo_s[srow][scol] = (unsigned int)lx | ((unsigned int)ly << 16);
    }
    BARRIER();   // sync1: A(0) staged

    for (int s = 0; s < ROWS_PER_BLOCK / 16; ++s) {
        float2 vn = v;
        if (s + 1 < ROWS_PER_BLOCK / 16) vn = zin[(s + 1) * 512 + tid];

        // ---- A fragments: lane m holds row m, k = kg*32 + qd*8 .. +8 ----
        bf16x8 ah[2], al[2];
        #pragma unroll
        for (int kg = 0; kg < 2; ++kg) {
            ah[kg] = *(const bf16x8*)&a_hi_s[m][kg * 32 + qd * 8];
            al[kg] = *(const bf16x8*)&a_lo_s[m][kg * 32 + qd * 8];
        }

        // ---- cross = z_hi.c_hi + z_hi.c_lo + z_lo.c_hi (near-fp32) ----
        f32x4 acc[4];
        #pragma unroll
        for (int t = 0; t < 4; ++t) acc[t] = (f32x4){0.f, 0.f, 0.f, 0.f};
        #pragma unroll
        for (int kg = 0; kg < 2; ++kg) {
            #pragma unroll
            for (int t = 0; t < 4; ++t) {
                acc[t] = __builtin_amdgcn_mfma_f32_16x16x32_bf16(ah[kg], bh[t][kg], acc[t], 0, 0, 0);
                acc[t] = __builtin_amdgcn_mfma_f32_16x16x32_bf16(ah[kg], bl[t][kg], acc[t], 0, 0, 0);
                acc[t] = __builtin_amdgcn_mfma_f32_16x16x32_bf16(al[kg], bh[t][kg], acc[t], 0, 0, 0);
            }
        }

        // ---- d' = csq - 2*cross (zsq dropped; cancels in softmax) ----
        float dd[4][4];
        #pragma unroll
        for (int t = 0; t < 4; ++t)
            #pragma unroll
            for (int r = 0; r < 4; ++r)
                dd[t][r] = __builtin_fmaf(-2.0f, acc[t][r], csq[t]);

        // ---- per-wave online-softmax partials (rows qd*4+r, 64 cols/wave) ----
        // shfl_xor masks 1,2,4,8 stay within the 16-lane qd-group (same rows).
        float mnw[4], sw[4], e[4][4], ped[4];
        #pragma unroll
        for (int r = 0; r < 4; ++r) {
            float mn0 = fminf(fminf(dd[0][r], dd[1][r]), fminf(dd[2][r], dd[3][r]));
            #pragma unroll
            for (int off = 1; off < 16; off <<= 1)
                mn0 = fminf(mn0, __shfl_xor(mn0, off, 64));
            mnw[r] = mn0;
        }
        #pragma unroll
        for (int t = 0; t < 4; ++t)
            #pragma unroll
            for (int r = 0; r < 4; ++r)
                e[t][r] = __expf(mnw[r] - dd[t][r]);
        #pragma unroll
        for (int r = 0; r < 4; ++r) {
            float s0 = (e[0][r] + e[1][r]) + (e[2][r] + e[3][r]);
            #pragma unroll
            for (int off = 1; off < 16; off <<= 1)
                s0 += __shfl_xor(s0, off, 64);
            sw[r] = s0;
            // loss partial: sum_t e*dd folded now so dd dies before the barrier
            ped[r] = __builtin_fmaf(e[0][r], dd[0][r],
                     __builtin_fmaf(e[1][r], dd[1][r],
                     __builtin_fmaf(e[2][r], dd[2][r], e[3][r] * dd[3][r])));
        }
        if (m == 0) {
            #pragma unroll
            for (int r = 0; r < 4; ++r)
                red_s[wave][qd * 4 + r] = make_float2(mnw[r], sw[r]);
        }
        BARRIER();   // sync2: partials visible; also fences A-frag reads of s

        // ---- stage next A subtile (safe: all frag reads of s are pre-sync2) ----
        if (s + 1 < ROWS_PER_BLOCK / 16) {
            zpart += vn.x * vn.x + vn.y * vn.y;
            unsigned short hx = f32_to_bf16_rne(vn.x);
            unsigned short lx = f32_to_bf16_rne(vn.x - bf16_bits_to_f32(hx));
            unsigned short hy = f32_to_bf16_rne(vn.y);
            unsigned short ly = f32_to_bf16_rne(vn.y - bf16_bits_to_f32(hy));
            *(unsigned int*)&a_hi_s[srow][scol] = (unsigned int)hx | ((unsigned int)hy << 16);
            *(unsigned int*)&a_lo_s[srow][scol] = (unsigned int)lx | ((unsigned int)ly << 16);
        }

        // ---- combine across waves (row = lane&15; broadcast reads, free) ----
        float mn = red_s[0][m].x;
        #pragma unroll
        for (int w2 = 1; w2 < 8; ++w2) mn = fminf(mn, red_s[w2][m].x);
        float S = 0.0f, msf = 0.0f;
        #pragma unroll
        for (int w2 = 0; w2 < 8; ++w2) {
            float2 p = red_s[w2][m];
            S = __builtin_fmaf(p.y, __expf(mn - p.x), S);
            if (w2 == wave) msf = p.x;
        }
        const float fself = __expf(mn - msf) / S;   // rescale for OUR wave's e

        // ---- distribute f to owning lanes, write q, accumulate loss ----
        float f4[4];
        #pragma unroll
        for (int r = 0; r < 4; ++r) f4[r] = __shfl(fself, qd * 4 + r, 64);

        const long rbase = rb + (long)s * 16;
        float* orow0 = q_out + (rbase + qd * 4) * K_CLUSTERS + wave * 64 + m;
        #pragma unroll
        for (int r = 0; r < 4; ++r) {
            float* orow = orow0 + (long)r * K_CLUSTERS;
            #pragma unroll
            for (int t = 0; t < 4; ++t) {
                const float qv = e[t][r] * f4[r];
                __builtin_nontemporal_store(qv, orow + t * 16);
            }
            lsum = __builtin_fmaf(f4[r], ped[r], lsum);
        }
        v = vn;
        if (s + 1 < ROWS_PER_BLOCK / 16) BARRIER();   // sync1 for next subtile
        // stores from this subtile drain under next subtile's MFMA (no vmcnt(0))
    }

    // ---- final loss reduction: zsq separable term + q*d' partials ----
    float tot = lsum + zpart;
    #pragma unroll
    for (int off = 1; off < 64; off <<= 1) tot += __shfl_xor(tot, off, 64);
    if (lane == 0) wloss_s[wave] = tot;
    __syncthreads();
    if (tid == 0) {
        float t0 = 0.f;
        #pragma unroll
        for (int w = 0; w < 8; ++w) t0 += wloss_s[w];
        atomicAdd(loss_out, t0 * inv_b);
    }
}

extern "C" void kernel_launch(void* const* d_in, const int* in_sizes, int n_in,
                              void* d_out, int out_size, void* d_ws, size_t ws_size,
                              hipStream_t stream) {
    const float* z = (const float*)d_in[0];
    const float* c = (const float*)d_in[1];
    const int B = in_sizes[0] / DIM;              // 131072
    float* q_out = (float*)d_out;
    float* loss_out = q_out + (size_t)B * K_CLUSTERS;

    char* ws = (char*)d_ws;
    short* c_hi = (short*)ws;                     // 64 KB
    short* c_lo = (short*)(ws + 65536);           // 64 KB
    float* c_sq = (float*)(ws + 131072);          // 2 KB

    prep_centers<<<(K_CLUSTERS * DIM) / 256, 256, 0, stream>>>(c, c_hi, c_lo, c_sq, loss_out);
    cluster_kernel<<<B / ROWS_PER_BLOCK, 512, 0, stream>>>(z, c_hi, c_lo, c_sq, q_out,
                                                           loss_out, 1.0f / (float)B);
}

// Round 2
// 343.050 us; speedup vs baseline: 1.0781x; 1.0781x over previous
//
#include <hip/hip_runtime.h>

typedef short bf16x8 __attribute__((ext_vector_type(8)));
typedef float f32x4 __attribute__((ext_vector_type(4)));

#define K_CLUSTERS 512
#define DIM 64
#define ROWS_PER_BLOCK 64   // 4 subtiles of 16 rows
#define NSUB 4

__device__ __forceinline__ unsigned short f32_to_bf16_rne(float f) {
    unsigned int u = __float_as_uint(f);
    u += 0x7fffu + ((u >> 16) & 1u);
    return (unsigned short)(u >> 16);
}
__device__ __forceinline__ float bf16_bits_to_f32(unsigned short h) {
    return __uint_as_float(((unsigned int)h) << 16);
}

// Centers -> bf16 hi/lo split + ||c||^2. Also zero-inits the loss accumulator.
__global__ void prep_centers(const float* __restrict__ c,
                             short* __restrict__ c_hi, short* __restrict__ c_lo,
                             float* __restrict__ c_sq, float* __restrict__ loss_out) {
    if (blockIdx.x == 0 && threadIdx.x == 0) loss_out[0] = 0.0f;
    int idx = blockIdx.x * 256 + threadIdx.x;   // covers 512*64
    float v = c[idx];
    unsigned short h = f32_to_bf16_rne(v);
    float hf = bf16_bits_to_f32(h);
    unsigned short l = f32_to_bf16_rne(v - hf);
    c_hi[idx] = (short)h;
    c_lo[idx] = (short)l;
    float s = v * v;
    #pragma unroll
    for (int off = 1; off < 64; off <<= 1) s += __shfl_xor(s, off, 64);
    if ((threadIdx.x & 63) == 0) c_sq[idx >> 6] = s;
}

// LDS-only barrier: lgkmcnt wait + s_barrier, NO vmcnt drain. After the
// prologue there are no global loads in the loop, so q-stores are never
// waited on until kernel end -- they drain under subsequent compute.
#define BARRIER() do {                                      \
    asm volatile("s_waitcnt lgkmcnt(0)" ::: "memory");      \
    __builtin_amdgcn_s_barrier();                           \
} while (0)

// 64 rows/block, 4 subtiles of 16; 8 waves x 64 clusters each.
// zsq cancels in softmax: softmax(-(zsq+csq-2zc)) == softmax(2zc-csq).
// loss = mean(zsq) + mean(sum_j q_j*(csq_j-2cross_j)).
// Per subtile: ONE barrier. Pre-barrier: MFMA -> dd -> per-wave (min, sum-exp)
// partials -> red_s[s&1]. Post-barrier: combine partials, q = exp(mn-dd)*invS.
// Only dd[16] lives across the barrier (no spill at the 128-VGPR cap).
__global__ __launch_bounds__(512, 4)
void cluster_kernel(const float* __restrict__ z,
                    const short* __restrict__ c_hi,
                    const short* __restrict__ c_lo,
                    const float* __restrict__ c_sq,
                    float* __restrict__ q_out,
                    float* __restrict__ loss_out,
                    float inv_b) {
    __shared__ __align__(16) short a_hi_s[NSUB][16][72];   // 144B rows = 9x16B
    __shared__ __align__(16) short a_lo_s[NSUB][16][72];
    __shared__ __align__(16) float2 red_s[2][8][16];       // [parity][wave][row]
    __shared__ float wloss_s[8];

    const int tid  = threadIdx.x;
    const int lane = tid & 63;
    const int wave = tid >> 6;
    const int m    = lane & 15;   // A row / B,C col within tile
    const int qd   = lane >> 4;   // quad
    const long rb  = (long)blockIdx.x * ROWS_PER_BLOCK;

    // ---- B fragments (64 cols/wave = 4 tiles): 64 VGPRs hi+lo. ----
    bf16x8 bh[4][2], bl[4][2];
    float csq[4];
    #pragma unroll
    for (int t = 0; t < 4; ++t) {
        const int col = wave * 64 + t * 16 + m;
        const long boff = (long)col * DIM + qd * 8;
        #pragma unroll
        for (int kg = 0; kg < 2; ++kg) {
            bh[t][kg] = *(const bf16x8*)(c_hi + boff + kg * 32);
            bl[t][kg] = *(const bf16x8*)(c_lo + boff + kg * 32);
        }
        csq[t] = c_sq[col];
    }

    // ---- prologue: load ALL z rows for this block, cvt+stage to LDS ----
    const float2* zin = (const float2*)(z + rb * DIM);   // 2048 float2
    const int srow = tid >> 5;
    const int scol = (tid & 31) * 2;
    float zpart = 0.0f;   // per-thread sum of z^2 (separable loss term)
    #pragma unroll
    for (int k = 0; k < NSUB; ++k) {
        float2 v = zin[k * 512 + tid];
        zpart += v.x * v.x + v.y * v.y;
        unsigned short hx = f32_to_bf16_rne(v.x);
        unsigned short lx = f32_to_bf16_rne(v.x - bf16_bits_to_f32(hx));
        unsigned short hy = f32_to_bf16_rne(v.y);
        unsigned short ly = f32_to_bf16_rne(v.y - bf16_bits_to_f32(hy));
        *(unsigned int*)&a_hi_s[k][srow][scol] = (unsigned int)hx | ((unsigned int)hy << 16);
        *(unsigned int*)&a_lo_s[k][srow][scol] = (unsigned int)lx | ((unsigned int)ly << 16);
    }
    BARRIER();   // A staged; A-tiles are read-only from here on

    float lsum = 0.0f;   // per-lane sum of q*(csq-2cross)

    for (int s = 0; s < NSUB; ++s) {
        // ---- A fragments: lane m holds row m, k = kg*32 + qd*8 .. +8 ----
        bf16x8 ah[2], al[2];
        #pragma unroll
        for (int kg = 0; kg < 2; ++kg) {
            ah[kg] = *(const bf16x8*)&a_hi_s[s][m][kg * 32 + qd * 8];
            al[kg] = *(const bf16x8*)&a_lo_s[s][m][kg * 32 + qd * 8];
        }

        // ---- cross = z_hi.c_hi + z_hi.c_lo + z_lo.c_hi (near-fp32) ----
        f32x4 acc[4];
        #pragma unroll
        for (int t = 0; t < 4; ++t) acc[t] = (f32x4){0.f, 0.f, 0.f, 0.f};
        #pragma unroll
        for (int kg = 0; kg < 2; ++kg) {
            #pragma unroll
            for (int t = 0; t < 4; ++t) {
                acc[t] = __builtin_amdgcn_mfma_f32_16x16x32_bf16(ah[kg], bh[t][kg], acc[t], 0, 0, 0);
                acc[t] = __builtin_amdgcn_mfma_f32_16x16x32_bf16(ah[kg], bl[t][kg], acc[t], 0, 0, 0);
                acc[t] = __builtin_amdgcn_mfma_f32_16x16x32_bf16(al[kg], bh[t][kg], acc[t], 0, 0, 0);
            }
        }

        // ---- dd = csq - 2*cross (zsq cancels in softmax) ----
        float dd[4][4];
        #pragma unroll
        for (int t = 0; t < 4; ++t)
            #pragma unroll
            for (int r = 0; r < 4; ++r)
                dd[t][r] = __builtin_fmaf(-2.0f, acc[t][r], csq[t]);

        // ---- per-wave partials: min + sum-exp over this wave's 64 cols ----
        // shfl_xor masks 1,2,4,8 stay within the 16-lane qd-group (same rows).
        float mnw[4], sw4[4];
        #pragma unroll
        for (int r = 0; r < 4; ++r) {
            float mn0 = fminf(fminf(dd[0][r], dd[1][r]), fminf(dd[2][r], dd[3][r]));
            #pragma unroll
            for (int off = 1; off < 16; off <<= 1)
                mn0 = fminf(mn0, __shfl_xor(mn0, off, 64));
            mnw[r] = mn0;
        }
        #pragma unroll
        for (int r = 0; r < 4; ++r) {
            float s0 = (__expf(mnw[r] - dd[0][r]) + __expf(mnw[r] - dd[1][r]))
                     + (__expf(mnw[r] - dd[2][r]) + __expf(mnw[r] - dd[3][r]));
            #pragma unroll
            for (int off = 1; off < 16; off <<= 1)
                s0 += __shfl_xor(s0, off, 64);
            sw4[r] = s0;
        }
        if (m == 0) {
            #pragma unroll
            for (int r = 0; r < 4; ++r)
                red_s[s & 1][wave][qd * 4 + r] = make_float2(mnw[r], sw4[r]);
        }
        BARRIER();   // partials visible (red_s parity s&1; reads of s-2's slot done)

        // ---- combine across waves (each lane: row = m; broadcast reads) ----
        float mn = red_s[s & 1][0][m].x;
        #pragma unroll
        for (int w2 = 1; w2 < 8; ++w2) mn = fminf(mn, red_s[s & 1][w2][m].x);
        float S = 0.0f;
        #pragma unroll
        for (int w2 = 0; w2 < 8; ++w2) {
            float2 p = red_s[s & 1][w2][m];
            S = __builtin_fmaf(p.y, __expf(mn - p.x), S);
        }
        const float invS = 1.0f / S;

        // ---- distribute per-row (mn, invS) to owning lanes ----
        float mnr[4], fsr[4];
        #pragma unroll
        for (int r = 0; r < 4; ++r) {
            mnr[r] = __shfl(mn,   qd * 4 + r, 64);
            fsr[r] = __shfl(invS, qd * 4 + r, 64);
        }

        // ---- q = exp(mn - dd) * invS; store + loss ----
        float* orow0 = q_out + (rb + (long)s * 16 + qd * 4) * K_CLUSTERS + wave * 64 + m;
        #pragma unroll
        for (int r = 0; r < 4; ++r) {
            float* orow = orow0 + (long)r * K_CLUSTERS;
            #pragma unroll
            for (int t = 0; t < 4; ++t) {
                const float qv = __expf(mnr[r] - dd[t][r]) * fsr[r];
                __builtin_nontemporal_store(qv, orow + t * 16);
                lsum = __builtin_fmaf(qv, dd[t][r], lsum);
            }
        }
        // no barrier here: next iteration's pre-barrier phase only reads
        // read-only A-tiles and writes red_s parity (s+1)&1, whose previous
        // readers all finished before this iteration's BARRIER.
    }

    // ---- final loss: zsq separable term + q*dd partials ----
    float tot = lsum + zpart;
    #pragma unroll
    for (int off = 1; off < 64; off <<= 1) tot += __shfl_xor(tot, off, 64);
    if (lane == 0) wloss_s[wave] = tot;
    __syncthreads();
    if (tid == 0) {
        float t0 = 0.f;
        #pragma unroll
        for (int w = 0; w < 8; ++w) t0 += wloss_s[w];
        atomicAdd(loss_out, t0 * inv_b);
    }
}

extern "C" void kernel_launch(void* const* d_in, const int* in_sizes, int n_in,
                              void* d_out, int out_size, void* d_ws, size_t ws_size,
                              hipStream_t stream) {
    const float* z = (const float*)d_in[0];
    const float* c = (const float*)d_in[1];
    const int B = in_sizes[0] / DIM;              // 131072
    float* q_out = (float*)d_out;
    float* loss_out = q_out + (size_t)B * K_CLUSTERS;

    char* ws = (char*)d_ws;
    short* c_hi = (short*)ws;                     // 64 KB
    short* c_lo = (short*)(ws + 65536);           // 64 KB
    float* c_sq = (float*)(ws + 131072);          // 2 KB

    prep_centers<<<(K_CLUSTERS * DIM) / 256, 256, 0, stream>>>(c, c_hi, c_lo, c_sq, loss_out);
    cluster_kernel<<<B / ROWS_PER_BLOCK, 512, 0, stream>>>(z, c_hi, c_lo, c_sq, q_out,
                                                           loss_out, 1.0f / (float)B);
}

// Round 3
// 337.523 us; speedup vs baseline: 1.0958x; 1.0164x over previous
//
#include <hip/hip_runtime.h>

typedef short bf16x8 __attribute__((ext_vector_type(8)));
typedef float f32x4 __attribute__((ext_vector_type(4)));

#define K_CLUSTERS 512
#define DIM 64
#define ROWS_PER_BLOCK 64   // 4 subtiles of 16 rows
#define NSUB 4
#define QPAD 520            // 512 + 8 dwords: +8 breaks pow2 bank stride

__device__ __forceinline__ unsigned short f32_to_bf16_rne(float f) {
    unsigned int u = __float_as_uint(f);
    u += 0x7fffu + ((u >> 16) & 1u);
    return (unsigned short)(u >> 16);
}
__device__ __forceinline__ float bf16_bits_to_f32(unsigned short h) {
    return __uint_as_float(((unsigned int)h) << 16);
}

// Centers -> bf16 hi/lo split + ||c||^2. Also zero-inits the loss accumulator.
__global__ void prep_centers(const float* __restrict__ c,
                             short* __restrict__ c_hi, short* __restrict__ c_lo,
                             float* __restrict__ c_sq, float* __restrict__ loss_out) {
    if (blockIdx.x == 0 && threadIdx.x == 0) loss_out[0] = 0.0f;
    int idx = blockIdx.x * 256 + threadIdx.x;   // covers 512*64
    float v = c[idx];
    unsigned short h = f32_to_bf16_rne(v);
    float hf = bf16_bits_to_f32(h);
    unsigned short l = f32_to_bf16_rne(v - hf);
    c_hi[idx] = (short)h;
    c_lo[idx] = (short)l;
    float s = v * v;
    #pragma unroll
    for (int off = 1; off < 64; off <<= 1) s += __shfl_xor(s, off, 64);
    if ((threadIdx.x & 63) == 0) c_sq[idx >> 6] = s;
}

// LDS-only barrier: lgkmcnt wait + s_barrier, NO vmcnt drain (q-stores are
// never waited on inside the loop; they drain under subsequent compute).
#define BARRIER() do {                                      \
    asm volatile("s_waitcnt lgkmcnt(0)" ::: "memory");      \
    __builtin_amdgcn_s_barrier();                           \
} while (0)

// 64 rows/block, 4 subtiles of 16; 8 waves x 64 clusters each.
// zsq cancels in softmax: softmax(-(zsq+csq-2zc)) == softmax(2zc-csq).
// loss = mean(zsq) + mean(sum_j q_j*(csq_j-2cross_j)).
// ROUND-3 CHANGE: q-store path. Was: nontemporal dword stores (both prior
// structures measured ~1.6 TB/s effective write BW — NT path suspected cap).
// Now: stage q per subtile in LDS, then PLAIN cached global_store_dwordx4,
// 64 lanes x 16 B = 1 KB contiguous per instruction (the fill kernel proves
// this path sustains 6.4 TB/s on this chip).
__global__ __launch_bounds__(512, 4)
void cluster_kernel(const float* __restrict__ z,
                    const short* __restrict__ c_hi,
                    const short* __restrict__ c_lo,
                    const float* __restrict__ c_sq,
                    float* __restrict__ q_out,
                    float* __restrict__ loss_out,
                    float inv_b) {
    __shared__ __align__(16) short a_hi_s[NSUB][16][72];   // 144B rows = 9x16B
    __shared__ __align__(16) short a_lo_s[NSUB][16][72];
    __shared__ __align__(16) float q_s[16][QPAD];          // 33.3 KB q transpose
    __shared__ __align__(16) float2 red_s[2][8][16];       // [parity][wave][row]
    __shared__ float wloss_s[8];

    const int tid  = threadIdx.x;
    const int lane = tid & 63;
    const int wave = tid >> 6;
    const int m    = lane & 15;   // A row / B,C col within tile
    const int qd   = lane >> 4;   // quad
    const long rb  = (long)blockIdx.x * ROWS_PER_BLOCK;

    // ---- B fragments (64 cols/wave = 4 tiles): 64 VGPRs hi+lo. ----
    bf16x8 bh[4][2], bl[4][2];
    float csq[4];
    #pragma unroll
    for (int t = 0; t < 4; ++t) {
        const int col = wave * 64 + t * 16 + m;
        const long boff = (long)col * DIM + qd * 8;
        #pragma unroll
        for (int kg = 0; kg < 2; ++kg) {
            bh[t][kg] = *(const bf16x8*)(c_hi + boff + kg * 32);
            bl[t][kg] = *(const bf16x8*)(c_lo + boff + kg * 32);
        }
        csq[t] = c_sq[col];
    }

    // ---- prologue: load ALL z rows for this block, cvt+stage to LDS ----
    const float2* zin = (const float2*)(z + rb * DIM);   // 2048 float2
    const int srow = tid >> 5;
    const int scol = (tid & 31) * 2;
    float zpart = 0.0f;   // per-thread sum of z^2 (separable loss term)
    #pragma unroll
    for (int k = 0; k < NSUB; ++k) {
        float2 v = zin[k * 512 + tid];
        zpart += v.x * v.x + v.y * v.y;
        unsigned short hx = f32_to_bf16_rne(v.x);
        unsigned short lx = f32_to_bf16_rne(v.x - bf16_bits_to_f32(hx));
        unsigned short hy = f32_to_bf16_rne(v.y);
        unsigned short ly = f32_to_bf16_rne(v.y - bf16_bits_to_f32(hy));
        *(unsigned int*)&a_hi_s[k][srow][scol] = (unsigned int)hx | ((unsigned int)hy << 16);
        *(unsigned int*)&a_lo_s[k][srow][scol] = (unsigned int)lx | ((unsigned int)ly << 16);
    }
    BARRIER();   // A staged; A-tiles are read-only from here on

    float lsum = 0.0f;   // per-lane sum of q*(csq-2cross)

    for (int s = 0; s < NSUB; ++s) {
        // ---- A fragments: lane m holds row m, k = kg*32 + qd*8 .. +8 ----
        bf16x8 ah[2], al[2];
        #pragma unroll
        for (int kg = 0; kg < 2; ++kg) {
            ah[kg] = *(const bf16x8*)&a_hi_s[s][m][kg * 32 + qd * 8];
            al[kg] = *(const bf16x8*)&a_lo_s[s][m][kg * 32 + qd * 8];
        }

        // ---- cross = z_hi.c_hi + z_hi.c_lo + z_lo.c_hi (near-fp32) ----
        f32x4 acc[4];
        #pragma unroll
        for (int t = 0; t < 4; ++t) acc[t] = (f32x4){0.f, 0.f, 0.f, 0.f};
        #pragma unroll
        for (int kg = 0; kg < 2; ++kg) {
            #pragma unroll
            for (int t = 0; t < 4; ++t) {
                acc[t] = __builtin_amdgcn_mfma_f32_16x16x32_bf16(ah[kg], bh[t][kg], acc[t], 0, 0, 0);
                acc[t] = __builtin_amdgcn_mfma_f32_16x16x32_bf16(ah[kg], bl[t][kg], acc[t], 0, 0, 0);
                acc[t] = __builtin_amdgcn_mfma_f32_16x16x32_bf16(al[kg], bh[t][kg], acc[t], 0, 0, 0);
            }
        }

        // ---- dd = csq - 2*cross (zsq cancels in softmax) ----
        float dd[4][4];
        #pragma unroll
        for (int t = 0; t < 4; ++t)
            #pragma unroll
            for (int r = 0; r < 4; ++r)
                dd[t][r] = __builtin_fmaf(-2.0f, acc[t][r], csq[t]);

        // ---- per-wave partials: min + sum-exp over this wave's 64 cols ----
        // shfl_xor masks 1,2,4,8 stay within the 16-lane qd-group (same rows).
        float mnw[4], sw4[4];
        #pragma unroll
        for (int r = 0; r < 4; ++r) {
            float mn0 = fminf(fminf(dd[0][r], dd[1][r]), fminf(dd[2][r], dd[3][r]));
            #pragma unroll
            for (int off = 1; off < 16; off <<= 1)
                mn0 = fminf(mn0, __shfl_xor(mn0, off, 64));
            mnw[r] = mn0;
        }
        #pragma unroll
        for (int r = 0; r < 4; ++r) {
            float s0 = (__expf(mnw[r] - dd[0][r]) + __expf(mnw[r] - dd[1][r]))
                     + (__expf(mnw[r] - dd[2][r]) + __expf(mnw[r] - dd[3][r]));
            #pragma unroll
            for (int off = 1; off < 16; off <<= 1)
                s0 += __shfl_xor(s0, off, 64);
            sw4[r] = s0;
        }
        if (m == 0) {
            #pragma unroll
            for (int r = 0; r < 4; ++r)
                red_s[s & 1][wave][qd * 4 + r] = make_float2(mnw[r], sw4[r]);
        }
        BARRIER();   // sync A: partials visible (also fences q_s reads of s-1)

        // ---- combine across waves (each lane: row = m; broadcast reads) ----
        float mn = red_s[s & 1][0][m].x;
        #pragma unroll
        for (int w2 = 1; w2 < 8; ++w2) mn = fminf(mn, red_s[s & 1][w2][m].x);
        float S = 0.0f;
        #pragma unroll
        for (int w2 = 0; w2 < 8; ++w2) {
            float2 p = red_s[s & 1][w2][m];
            S = __builtin_fmaf(p.y, __expf(mn - p.x), S);
        }
        const float invS = 1.0f / S;

        // ---- distribute per-row (mn, invS) to owning lanes ----
        float mnr[4], fsr[4];
        #pragma unroll
        for (int r = 0; r < 4; ++r) {
            mnr[r] = __shfl(mn,   qd * 4 + r, 64);
            fsr[r] = __shfl(invS, qd * 4 + r, 64);
        }

        // ---- q = exp(mn - dd) * invS -> LDS (transpose for coalescing) ----
        // Write banks: row stride 520 ≡ 8 (mod 32); within an instr the 4
        // qd-groups hit each bank exactly 2x -> free (m136: 2-way = 1.02x).
        #pragma unroll
        for (int r = 0; r < 4; ++r) {
            const int row = qd * 4 + r;
            #pragma unroll
            for (int t = 0; t < 4; ++t) {
                const float qv = __expf(mnr[r] - dd[t][r]) * fsr[r];
                q_s[row][wave * 64 + t * 16 + m] = qv;
                lsum = __builtin_fmaf(qv, dd[t][r], lsum);
            }
        }
        BARRIER();   // sync B: q_s complete

        // ---- coalesced q write: wave owns rows [2w, 2w+2), PLAIN dwordx4,
        //      64 lanes x 16 B = 1 KB contiguous per store instruction ----
        const long rbase = rb + (long)s * 16;
        #pragma unroll
        for (int rr = 0; rr < 2; ++rr) {
            const int row = wave * 2 + rr;
            const f32x4* src = (const f32x4*)&q_s[row][0];   // 16B-aligned (QPAD%4==0)
            f32x4 v0 = src[lane];        // ds_read_b128, consecutive lanes
            f32x4 v1 = src[64 + lane];
            f32x4* dst = (f32x4*)(q_out + (rbase + row) * K_CLUSTERS);
            dst[lane]      = v0;
            dst[64 + lane] = v1;
        }
        // next subtile's q_s writes happen only after its sync A barrier, by
        // which time every wave's q_s reads here have completed (the data is
        // consumed by the stores, which wait lgkmcnt before issuing).
    }

    // ---- final loss: zsq separable term + q*dd partials ----
    float tot = lsum + zpart;
    #pragma unroll
    for (int off = 1; off < 64; off <<= 1) tot += __shfl_xor(tot, off, 64);
    if (lane == 0) wloss_s[wave] = tot;
    __syncthreads();
    if (tid == 0) {
        float t0 = 0.f;
        #pragma unroll
        for (int w = 0; w < 8; ++w) t0 += wloss_s[w];
        atomicAdd(loss_out, t0 * inv_b);
    }
}

extern "C" void kernel_launch(void* const* d_in, const int* in_sizes, int n_in,
                              void* d_out, int out_size, void* d_ws, size_t ws_size,
                              hipStream_t stream) {
    const float* z = (const float*)d_in[0];
    const float* c = (const float*)d_in[1];
    const int B = in_sizes[0] / DIM;              // 131072
    float* q_out = (float*)d_out;
    float* loss_out = q_out + (size_t)B * K_CLUSTERS;

    char* ws = (char*)d_ws;
    short* c_hi = (short*)ws;                     // 64 KB
    short* c_lo = (short*)(ws + 65536);           // 64 KB
    float* c_sq = (float*)(ws + 131072);          // 2 KB

    prep_centers<<<(K_CLUSTERS * DIM) / 256, 256, 0, stream>>>(c, c_hi, c_lo, c_sq, loss_out);
    cluster_kernel<<<B / ROWS_PER_BLOCK, 512, 0, stream>>>(z, c_hi, c_lo, c_sq, q_out,
                                                           loss_out, 1.0f / (float)B);
}